// Round 7
// baseline (198.861 us; speedup 1.0000x reference)
//
#include <hip/hip_runtime.h>
#include <hip/hip_bf16.h>

#define LLEN 4096
#define BATCH 16
#define NROWS 65536   // BATCH*LLEN
#define DDIM 128
#define JDIM 256      // 2*D
#define KM1 255       // K-1
#define BR 64         // rows per block
#define TPITCH 266    // t LDS pitch in halfs (133 dwords -> odd bank stride)

typedef __attribute__((ext_vector_type(8))) _Float16 h8;
typedef __attribute__((ext_vector_type(4))) _Float16 h4;
typedef __attribute__((ext_vector_type(4))) float f4v;

__device__ __forceinline__ float clampf(float x, float lo, float hi) {
  return fminf(fmaxf(x, lo), hi);
}
__device__ __forceinline__ float tanh_fast(float x) {
  float e = __expf(2.0f * x);
  return 1.0f - 2.0f / (e + 1.0f);
}

// ---------------- kW: pack W1^T, W2^T into per-wave-contiguous fp16 MFMA fragments ----------------
// frag = 64 lanes x 8 halfs (1 KB). lane=(g*16+rr): value = WT[tile*16+rr][ks*32+8g+i].
// W1P: frag (jt*4+ks), jt<16, ks<4. W2P: frag (kt*8+ks), kt<16, ks<8 (k=255 zero-pad).
__global__ void kW(const float* __restrict__ W1, const float* __restrict__ W2,
                   _Float16* __restrict__ W1P, _Float16* __restrict__ W2P) {
  const int T = blockIdx.x * 256 + threadIdx.x;   // 192 frags * 64 lanes
  if (T >= 192 * 64) return;
  const int frag = T >> 6, lane = T & 63;
  const int rr = lane & 15, g = lane >> 4;
  if (frag < 64) {
    const int jt = frag >> 2, ks = frag & 3;
    _Float16* base = W1P + (size_t)frag * 512 + lane * 8;
    #pragma unroll
    for (int i = 0; i < 8; ++i)
      base[i] = (_Float16)W1[(ks * 32 + 8 * g + i) * JDIM + jt * 16 + rr];
  } else {
    const int f2 = frag - 64;
    const int kt = f2 >> 3, ks = f2 & 7;
    const int k = kt * 16 + rr;
    _Float16* base = W2P + (size_t)f2 * 512 + lane * 8;
    #pragma unroll
    for (int i = 0; i < 8; ++i)
      base[i] = (k < KM1) ? (_Float16)W2[(ks * 32 + 8 * g + i) * KM1 + k] : (_Float16)0.0f;
  }
}

// ---------------- kF: fused GEMM1(tanh) -> LDS t -> GEMM2 -> exp partial sums ----------------
// 64 rows/block, 8 waves: mw = M-quarter (j/k), rw = row-half. One barrier. No atomics.
// launch_bounds(512,8): 64-VGPR budget -> 4 blocks/CU (32 waves/CU), grid 1024 = 4/CU exactly.
__launch_bounds__(512, 8)
__global__ void kF(const float* __restrict__ X,
                   const _Float16* __restrict__ W1P, const _Float16* __restrict__ W2P,
                   const float* __restrict__ b1, const float* __restrict__ Wr,
                   const float* __restrict__ mask,
                   float* __restrict__ partE, float* __restrict__ partR) {
  __shared__ _Float16 tS[BR * TPITCH];   // 34,048 B
  __shared__ float rS[BR];

  const int tid  = threadIdx.x;
  const int lane = tid & 63, wid = tid >> 6;
  const int rr = lane & 15, g = lane >> 4;
  const int mw = wid & 3;        // M quarter (j in phase1, k in phase2)
  const int rw = wid >> 2;       // row half (32 rows)
  const int blk = blockIdx.x;
  const int b = blk >> 6;        // 64 blocks per batch
  const int r_base = blk * BR;

  f4v acc[4][2];
  #pragma unroll
  for (int m = 0; m < 4; ++m)
    #pragma unroll
    for (int n = 0; n < 2; ++n) { acc[m][n][0]=0.f; acc[m][n][1]=0.f; acc[m][n][2]=0.f; acc[m][n][3]=0.f; }
  float rp[2] = {0.f, 0.f};

  // ---- phase 1: t = tanh(X@W1+b1), M=j(256), N=rows(64), K=d(128). Pipelined, no barriers. ----
  h8 Wc[4], Wn[4];
  #pragma unroll
  for (int mf = 0; mf < 4; ++mf)
    Wc[mf] = *reinterpret_cast<const h8*>(W1P + (size_t)((mw * 4 + mf) * 4) * 512 + lane * 8);
  float4 xc[2][2], xn[2][2];
  #pragma unroll
  for (int nf = 0; nf < 2; ++nf) {
    const float* xp = X + (size_t)(r_base + rw * 32 + nf * 16 + rr) * DDIM + 8 * g;
    xc[nf][0] = *reinterpret_cast<const float4*>(xp);
    xc[nf][1] = *reinterpret_cast<const float4*>(xp + 4);
  }
  #pragma unroll
  for (int ks = 0; ks < 4; ++ks) {
    if (ks < 3) {
      #pragma unroll
      for (int mf = 0; mf < 4; ++mf)
        Wn[mf] = *reinterpret_cast<const h8*>(W1P + (size_t)((mw * 4 + mf) * 4 + ks + 1) * 512 + lane * 8);
      #pragma unroll
      for (int nf = 0; nf < 2; ++nf) {
        const float* xp = X + (size_t)(r_base + rw * 32 + nf * 16 + rr) * DDIM + (ks + 1) * 32 + 8 * g;
        xn[nf][0] = *reinterpret_cast<const float4*>(xp);
        xn[nf][1] = *reinterpret_cast<const float4*>(xp + 4);
      }
    }
    h8 Bx[2];
    #pragma unroll
    for (int nf = 0; nf < 2; ++nf) {
      const float xv[8] = {xc[nf][0].x, xc[nf][0].y, xc[nf][0].z, xc[nf][0].w,
                           xc[nf][1].x, xc[nf][1].y, xc[nf][1].z, xc[nf][1].w};
      #pragma unroll
      for (int i = 0; i < 8; ++i) Bx[nf][i] = (_Float16)xv[i];
      if (mw == 0) {
        const float4 w0 = *reinterpret_cast<const float4*>(Wr + ks * 32 + 8 * g);
        const float4 w1 = *reinterpret_cast<const float4*>(Wr + ks * 32 + 8 * g + 4);
        rp[nf] += xv[0]*w0.x + xv[1]*w0.y + xv[2]*w0.z + xv[3]*w0.w
                + xv[4]*w1.x + xv[5]*w1.y + xv[6]*w1.z + xv[7]*w1.w;
      }
    }
    #pragma unroll
    for (int mf = 0; mf < 4; ++mf)
      #pragma unroll
      for (int nf = 0; nf < 2; ++nf)
        acc[mf][nf] = __builtin_amdgcn_mfma_f32_16x16x32_f16(Wc[mf], Bx[nf], acc[mf][nf], 0, 0, 0);
    if (ks < 3) {
      #pragma unroll
      for (int mf = 0; mf < 4; ++mf) Wc[mf] = Wn[mf];
      #pragma unroll
      for (int nf = 0; nf < 2; ++nf) { xc[nf][0] = xn[nf][0]; xc[nf][1] = xn[nf][1]; }
    }
  }

  // hoist phase-2 weight frags: issue now so they land during tanh + barrier
  #pragma unroll
  for (int mf = 0; mf < 4; ++mf)
    Wc[mf] = *reinterpret_cast<const h8*>(W2P + (size_t)((mw * 4 + mf) * 8) * 512 + lane * 8);

  // epilogue 1: bias + tanh -> fp16 tS; fused r-dot -> rS
  #pragma unroll
  for (int mf = 0; mf < 4; ++mf) {
    const int j0 = (mw * 4 + mf) * 16 + 4 * g;
    const float4 bv = *reinterpret_cast<const float4*>(b1 + j0);
    const float bva[4] = {bv.x, bv.y, bv.z, bv.w};
    #pragma unroll
    for (int nf = 0; nf < 2; ++nf) {
      const int rl = rw * 32 + nf * 16 + rr;
      h4 o;
      #pragma unroll
      for (int reg = 0; reg < 4; ++reg)
        o[reg] = (_Float16)tanh_fast(acc[mf][nf][reg] + bva[reg]);
      *reinterpret_cast<h4*>(&tS[rl * TPITCH + j0]) = o;
    }
  }
  if (mw == 0) {
    #pragma unroll
    for (int nf = 0; nf < 2; ++nf) {
      rp[nf] += __shfl_xor(rp[nf], 16, 64);
      rp[nf] += __shfl_xor(rp[nf], 32, 64);
    }
    if (g == 0) {
      #pragma unroll
      for (int nf = 0; nf < 2; ++nf) rS[rw * 32 + nf * 16 + rr] = rp[nf];
    }
  }
  // re-zero accumulators for phase 2
  #pragma unroll
  for (int m = 0; m < 4; ++m)
    #pragma unroll
    for (int n = 0; n < 2; ++n) { acc[m][n][0]=0.f; acc[m][n][1]=0.f; acc[m][n][2]=0.f; acc[m][n][3]=0.f; }
  __syncthreads();   // the only barrier

  // hoist epilogue-2 scalars (overlap with phase-2 MFMAs)
  float mv[2], rv[2];
  #pragma unroll
  for (int nf = 0; nf < 2; ++nf) {
    const int rl = rw * 32 + nf * 16 + rr;
    mv[nf] = mask[r_base + rl];
    rv[nf] = rS[rl];
  }

  // ---- phase 2: logits = t@W2, M=k(256), N=rows(64), K=j(256). Pipelined, no barriers. ----
  #pragma unroll
  for (int ks = 0; ks < 8; ++ks) {
    if (ks < 7) {
      #pragma unroll
      for (int mf = 0; mf < 4; ++mf)
        Wn[mf] = *reinterpret_cast<const h8*>(W2P + (size_t)((mw * 4 + mf) * 8 + ks + 1) * 512 + lane * 8);
    }
    h8 Bt[2];
    #pragma unroll
    for (int nf = 0; nf < 2; ++nf) {
      const int rl = rw * 32 + nf * 16 + rr;
      Bt[nf] = *reinterpret_cast<const h8*>(&tS[rl * TPITCH + ks * 32 + 8 * g]);
    }
    #pragma unroll
    for (int mf = 0; mf < 4; ++mf)
      #pragma unroll
      for (int nf = 0; nf < 2; ++nf)
        acc[mf][nf] = __builtin_amdgcn_mfma_f32_16x16x32_f16(Wc[mf], Bt[nf], acc[mf][nf], 0, 0, 0);
    if (ks < 7) {
      #pragma unroll
      for (int mf = 0; mf < 4; ++mf) Wc[mf] = Wn[mf];
    }
  }

  // epilogue 2: masked exp; per-k sums of e and e*r over this wave's 32 rows; partial write
  float sE[4][4], sR[4][4];
  #pragma unroll
  for (int mf = 0; mf < 4; ++mf)
    #pragma unroll
    for (int reg = 0; reg < 4; ++reg) { sE[mf][reg] = 0.f; sR[mf][reg] = 0.f; }
  #pragma unroll
  for (int nf = 0; nf < 2; ++nf) {
    const float addm = (1.0f - mv[nf]) * (-1e30f);
    #pragma unroll
    for (int mf = 0; mf < 4; ++mf)
      #pragma unroll
      for (int reg = 0; reg < 4; ++reg) {
        const float e = __expf(mv[nf] * acc[mf][nf][reg] + addm);
        sE[mf][reg] += e;
        sR[mf][reg] += e * rv[nf];
      }
  }
  #pragma unroll
  for (int off = 1; off < 16; off <<= 1)
    #pragma unroll
    for (int mf = 0; mf < 4; ++mf)
      #pragma unroll
      for (int reg = 0; reg < 4; ++reg) {
        sE[mf][reg] += __shfl_xor(sE[mf][reg], off, 64);
        sR[mf][reg] += __shfl_xor(sR[mf][reg], off, 64);
      }
  if (rr == 0) {
    const int s = (blk & 63) * 2 + rw;            // 0..127 within batch
    float* pE = partE + (size_t)s * 4096 + b * 256;
    float* pR = partR + (size_t)s * 4096 + b * 256;
    #pragma unroll
    for (int mf = 0; mf < 4; ++mf)
      #pragma unroll
      for (int reg = 0; reg < 4; ++reg) {
        const int k = (mw * 4 + mf) * 16 + 4 * g + reg;
        pE[k] = sE[mf][reg];
        pR[k] = sR[mf][reg];
      }
  }
}

// ---------------- kC: reduce partials -> mu -> softmax -> cumsum -> cdf params ----------------
__global__ void kC(const float* __restrict__ partE, const float* __restrict__ partR,
                   const float* __restrict__ br, float* __restrict__ params) {
  __shared__ float red[256];
  __shared__ float sm[256];
  const int b = blockIdx.x;
  const int k = threadIdx.x;
  float v = 0.0f;
  if (k > 0) {
    const size_t idx = (size_t)b * 256 + (k - 1);
    float e0 = 0.f, e1 = 0.f, e2 = 0.f, e3 = 0.f;
    float r0 = 0.f, r1 = 0.f, r2 = 0.f, r3 = 0.f;
    #pragma unroll 4
    for (int s = 0; s < 128; s += 4) {
      e0 += partE[(size_t)(s + 0) * 4096 + idx];
      e1 += partE[(size_t)(s + 1) * 4096 + idx];
      e2 += partE[(size_t)(s + 2) * 4096 + idx];
      e3 += partE[(size_t)(s + 3) * 4096 + idx];
      r0 += partR[(size_t)(s + 0) * 4096 + idx];
      r1 += partR[(size_t)(s + 1) * 4096 + idx];
      r2 += partR[(size_t)(s + 2) * 4096 + idx];
      r3 += partR[(size_t)(s + 3) * 4096 + idx];
    }
    v = ((r0 + r1) + (r2 + r3)) / ((e0 + e1) + (e2 + e3)) + br[0];
  }
  red[k] = v; __syncthreads();
  #pragma unroll
  for (int off = 128; off > 0; off >>= 1) {
    if (k < off) red[k] = fmaxf(red[k], red[k + off]);
    __syncthreads();
  }
  const float vmax = red[0];
  __syncthreads();
  const float e = expf(v - vmax);
  red[k] = e; __syncthreads();
  #pragma unroll
  for (int off = 128; off > 0; off >>= 1) {
    if (k < off) red[k] += red[k + off];
    __syncthreads();
  }
  const float tot = red[0];
  __syncthreads();
  sm[k] = e / tot; __syncthreads();
  for (int off = 1; off < 256; off <<= 1) {
    const float add = (k >= off) ? sm[k - off] : 0.0f;
    __syncthreads();
    sm[k] += add;
    __syncthreads();
  }
  if (k < KM1) {
    const float m  = clampf(sm[k], 1e-4f, 0.9999f);
    const float a  = clampf(m - 0.0625f, 0.0f, 0.875f);
    const float bb = clampf(a + 0.125f, 0.125f, 1.0f);
    const float ba = bb - a, ma = m - a, bm = bb - m;
    float* p = params + ((size_t)b * KM1 + k) * 8;
    *reinterpret_cast<float4*>(p)     = make_float4(m, a, bb, ma / ba);
    *reinterpret_cast<float4*>(p + 4) = make_float4(1.0f / ma, bm / ba, 1.0f / bm, 0.0f);
  }
}

// ---------------- kD: gamma_scaled + almat (float4 stores) ----------------
__launch_bounds__(256)
__global__ void kD(const float* __restrict__ params, float* __restrict__ gamma,
                   float* __restrict__ almat) {
  __shared__ float P[KM1][8];
  __shared__ float gl[256];
  const int lc = blockIdx.x, b = blockIdx.y;
  const int tid = threadIdx.x;
  if (tid < KM1) {
    const float* p = params + ((size_t)b * KM1 + tid) * 8;
    *reinterpret_cast<float4*>(&P[tid][0]) = *reinterpret_cast<const float4*>(p);
    *reinterpret_cast<float4*>(&P[tid][4]) = *reinterpret_cast<const float4*>(p + 4);
  }
  __syncthreads();
  const int l = lc * 256 + tid;
  const float x = (float)l * (1.0f / 4095.0f);
  float g = 0.0f;
  for (int k = 0; k < KM1; ++k) {
    const float m = P[k][0], a = P[k][1], bb = P[k][2], cL = P[k][3];
    const float iMA = P[k][4], cR = P[k][5], iBM = P[k][6];
    float u = clampf((x - a) * iMA, 0.0f, 1.0f);
    u = u * u; u = u * u; u = u * u; u = u * u;
    float w = clampf((bb - x) * iBM, 0.0f, 1.0f);
    w = w * w; w = w * w; w = w * w; w = w * w;
    const float left  = cL * u;
    const float right = 1.0f - cR * w;
    g += (x <= m) ? left : right;
  }
  gamma[(size_t)b * LLEN + l] = g;
  gl[tid] = g;
  __syncthreads();
  // almat: thread -> 4 consecutive k, 64 i-steps; wave writes 1 KB contiguous
  const int kg = (tid & 63) * 4;
  const int i0 = tid >> 6;
  const float kg0 = (float)kg;
  const size_t base = ((size_t)b * LLEN + (size_t)lc * 256) * 256;
  for (int s = 0; s < 64; ++s) {
    const int i = s * 4 + i0;
    const float gv = gl[i];
    float4 v;
    v.x = fmaxf(1.0f - fabsf(gv - kg0), 0.0f);
    v.y = fmaxf(1.0f - fabsf(gv - (kg0 + 1.0f)), 0.0f);
    v.z = fmaxf(1.0f - fabsf(gv - (kg0 + 2.0f)), 0.0f);
    v.w = fmaxf(1.0f - fabsf(gv - (kg0 + 3.0f)), 0.0f);
    *reinterpret_cast<float4*>(&almat[base + (size_t)i * 256 + kg]) = v;
  }
}

extern "C" void kernel_launch(void* const* d_in, const int* in_sizes, int n_in,
                              void* d_out, int out_size, void* d_ws, size_t ws_size,
                              hipStream_t stream) {
  const float* X    = (const float*)d_in[0];
  const float* mask = (const float*)d_in[1];
  const float* W1   = (const float*)d_in[2];
  const float* b1   = (const float*)d_in[3];
  const float* W2   = (const float*)d_in[4];
  const float* Wr   = (const float*)d_in[5];
  const float* br   = (const float*)d_in[6];
  float* out   = (float*)d_out;
  float* gamma = out;
  float* almat = out + NROWS;
  // partial sums aliased in almat region (overwritten by kD afterwards):
  float* partE = almat;                    // [128][4096] f32 = 2 MB
  float* partR = almat + (size_t)128 * 4096;
  // workspace
  float* params = (float*)d_ws;                                  // [16][255][8]
  _Float16* W1P = (_Float16*)(params + (size_t)BATCH * KM1 * 8); // 64 frags * 512 halfs
  _Float16* W2P = W1P + 64 * 512;                                // 128 frags * 512 halfs

  kW<<<48, 256, 0, stream>>>(W1, W2, W1P, W2P);
  kF<<<NROWS / BR, 512, 0, stream>>>(X, W1P, W2P, b1, Wr, mask, partE, partR);
  kC<<<BATCH, 256, 0, stream>>>(partE, partR, br, params);
  kD<<<dim3(16, BATCH), 256, 0, stream>>>(params, gamma, almat);
}

// Round 8
// 87.325 us; speedup vs baseline: 2.2773x; 2.2773x over previous
//
#include <hip/hip_runtime.h>
#include <hip/hip_bf16.h>

#define LLEN 4096
#define BATCH 16
#define NROWS 65536   // BATCH*LLEN
#define DDIM 128
#define JDIM 256      // 2*D
#define KM1 255       // K-1
#define BR 64         // rows per block
#define TPITCH 266    // t LDS pitch in halfs (133 dwords -> odd bank stride)

typedef __attribute__((ext_vector_type(8))) _Float16 h8;
typedef __attribute__((ext_vector_type(4))) _Float16 h4;
typedef __attribute__((ext_vector_type(4))) float f4v;

typedef __attribute__((address_space(3))) void lds_t;
typedef __attribute__((address_space(1))) const void gbl_t;
__device__ __forceinline__ void g2l16(const void* g, void* l) {
  // async global->LDS, 16B per lane; LDS dest = wave-uniform base + lane*16
  __builtin_amdgcn_global_load_lds((gbl_t*)g, (lds_t*)l, 16, 0, 0);
}

__device__ __forceinline__ float clampf(float x, float lo, float hi) {
  return fminf(fmaxf(x, lo), hi);
}
__device__ __forceinline__ float tanh_fast(float x) {
  float e = __expf(2.0f * x);
  return 1.0f - 2.0f / (e + 1.0f);
}

// ---------------- kW: pack W1^T, W2^T into per-wave-contiguous fp16 MFMA fragments ----------------
// frag = 64 lanes x 8 halfs (1 KB). lane=(g*16+rr): value = WT[tile*16+rr][ks*32+8g+i].
// W1P: frag (jt*4+ks), jt<16, ks<4. W2P: frag (kt*8+ks), kt<16, ks<8 (k=255 zero-pad).
__global__ void kW(const float* __restrict__ W1, const float* __restrict__ W2,
                   _Float16* __restrict__ W1P, _Float16* __restrict__ W2P) {
  const int T = blockIdx.x * 256 + threadIdx.x;   // 192 frags * 64 lanes
  if (T >= 192 * 64) return;
  const int frag = T >> 6, lane = T & 63;
  const int rr = lane & 15, g = lane >> 4;
  if (frag < 64) {
    const int jt = frag >> 2, ks = frag & 3;
    _Float16* base = W1P + (size_t)frag * 512 + lane * 8;
    #pragma unroll
    for (int i = 0; i < 8; ++i)
      base[i] = (_Float16)W1[(ks * 32 + 8 * g + i) * JDIM + jt * 16 + rr];
  } else {
    const int f2 = frag - 64;
    const int kt = f2 >> 3, ks = f2 & 7;
    const int k = kt * 16 + rr;
    _Float16* base = W2P + (size_t)f2 * 512 + lane * 8;
    #pragma unroll
    for (int i = 0; i < 8; ++i)
      base[i] = (k < KM1) ? (_Float16)W2[(ks * 32 + 8 * g + i) * KM1 + k] : (_Float16)0.0f;
  }
}

// ---------------- kF: fused GEMM1(tanh) -> LDS t -> GEMM2 -> exp partial sums ----------------
// 64 rows/block, 8 waves: mw = M-quarter (j/k), rw = row-half.
// Weights staged via global_load_lds double-buffer, issued one ks ahead (m97 structure).
__launch_bounds__(512, 4)
__global__ void kF(const float* __restrict__ X,
                   const _Float16* __restrict__ W1P, const _Float16* __restrict__ W2P,
                   const float* __restrict__ b1, const float* __restrict__ Wr,
                   const float* __restrict__ mask,
                   float* __restrict__ partE, float* __restrict__ partR) {
  __shared__ _Float16 tS[BR * TPITCH];   // 34,048 B
  __shared__ _Float16 stg[2][8192];      // 2 x 16 KB weight-slice double buffer
  __shared__ float rS[BR];

  const int tid  = threadIdx.x;
  const int lane = tid & 63, wid = tid >> 6;
  const int rr = lane & 15, g = lane >> 4;
  const int mw = wid & 3;        // M quarter (j in phase1, k in phase2)
  const int rw = wid >> 2;       // row half (32 rows)
  const int blk = blockIdx.x;
  const int b = blk >> 6;        // 64 blocks per batch
  const int r_base = blk * BR;

  // stage slice ks of a frag-packed weight plane into stg[buf]:
  // wave wid stages tiles (wid) and (wid+8); LDS layout [tile16][lane64][8 halfs]
  auto stage = [&](const _Float16* WP, int nsl, int ks, int buf) {
    const _Float16* g0 = WP + ((size_t)(wid * nsl + ks)) * 512 + lane * 8;
    const _Float16* g1 = WP + ((size_t)((wid + 8) * nsl + ks)) * 512 + lane * 8;
    g2l16(g0, &stg[buf][wid * 512]);
    g2l16(g1, &stg[buf][(wid + 8) * 512]);
  };

  f4v acc[4][2];
  #pragma unroll
  for (int m = 0; m < 4; ++m)
    #pragma unroll
    for (int n = 0; n < 2; ++n) { acc[m][n][0]=0.f; acc[m][n][1]=0.f; acc[m][n][2]=0.f; acc[m][n][3]=0.f; }
  float rp[2] = {0.f, 0.f};

  // ---- prologue: stage W1 slice 0; prefetch X slice 0 ----
  stage(W1P, 4, 0, 0);
  float4 xc[2][2], xn[2][2];
  #pragma unroll
  for (int nf = 0; nf < 2; ++nf) {
    const float* xp = X + (size_t)(r_base + rw * 32 + nf * 16 + rr) * DDIM + 8 * g;
    xc[nf][0] = *reinterpret_cast<const float4*>(xp);
    xc[nf][1] = *reinterpret_cast<const float4*>(xp + 4);
  }
  __syncthreads();   // drain: slice 0 resident

  // ---- phase 1: t = tanh(X@W1+b1), M=j(256), N=rows(64), K=d(128) ----
  #pragma unroll
  for (int ks = 0; ks < 4; ++ks) {
    if (ks < 3) {
      stage(W1P, 4, ks + 1, (ks + 1) & 1);   // issue next slice early
      #pragma unroll
      for (int nf = 0; nf < 2; ++nf) {
        const float* xp = X + (size_t)(r_base + rw * 32 + nf * 16 + rr) * DDIM + (ks + 1) * 32 + 8 * g;
        xn[nf][0] = *reinterpret_cast<const float4*>(xp);
        xn[nf][1] = *reinterpret_cast<const float4*>(xp + 4);
      }
    }
    h8 Wf[4];
    #pragma unroll
    for (int mf = 0; mf < 4; ++mf)
      Wf[mf] = *reinterpret_cast<const h8*>(&stg[ks & 1][(size_t)(mw * 4 + mf) * 512 + lane * 8]);
    h8 Bx[2];
    #pragma unroll
    for (int nf = 0; nf < 2; ++nf) {
      const float xv[8] = {xc[nf][0].x, xc[nf][0].y, xc[nf][0].z, xc[nf][0].w,
                           xc[nf][1].x, xc[nf][1].y, xc[nf][1].z, xc[nf][1].w};
      #pragma unroll
      for (int i = 0; i < 8; ++i) Bx[nf][i] = (_Float16)xv[i];
      if (mw == 0) {
        const float4 w0 = *reinterpret_cast<const float4*>(Wr + ks * 32 + 8 * g);
        const float4 w1 = *reinterpret_cast<const float4*>(Wr + ks * 32 + 8 * g + 4);
        rp[nf] += xv[0]*w0.x + xv[1]*w0.y + xv[2]*w0.z + xv[3]*w0.w
                + xv[4]*w1.x + xv[5]*w1.y + xv[6]*w1.z + xv[7]*w1.w;
      }
    }
    #pragma unroll
    for (int mf = 0; mf < 4; ++mf)
      #pragma unroll
      for (int nf = 0; nf < 2; ++nf)
        acc[mf][nf] = __builtin_amdgcn_mfma_f32_16x16x32_f16(Wf[mf], Bx[nf], acc[mf][nf], 0, 0, 0);
    if (ks < 3) {
      __syncthreads();   // drain: slice ks+1 ready; buffer (ks&1) reusable
      #pragma unroll
      for (int nf = 0; nf < 2; ++nf) { xc[nf][0] = xn[nf][0]; xc[nf][1] = xn[nf][1]; }
    }
  }

  // issue W2 slice 0 into buf0 (buf0 idle since ks=2 barrier; buf1 may still be read -> untouched)
  stage(W2P, 8, 0, 0);

  // epilogue 1: bias + tanh -> fp16 tS; fused r-dot -> rS
  #pragma unroll
  for (int mf = 0; mf < 4; ++mf) {
    const int j0 = (mw * 4 + mf) * 16 + 4 * g;
    const float4 bv = *reinterpret_cast<const float4*>(b1 + j0);
    const float bva[4] = {bv.x, bv.y, bv.z, bv.w};
    #pragma unroll
    for (int nf = 0; nf < 2; ++nf) {
      const int rl = rw * 32 + nf * 16 + rr;
      h4 o;
      #pragma unroll
      for (int reg = 0; reg < 4; ++reg)
        o[reg] = (_Float16)tanh_fast(acc[mf][nf][reg] + bva[reg]);
      *reinterpret_cast<h4*>(&tS[rl * TPITCH + j0]) = o;
    }
  }
  if (mw == 0) {
    #pragma unroll
    for (int nf = 0; nf < 2; ++nf) {
      rp[nf] += __shfl_xor(rp[nf], 16, 64);
      rp[nf] += __shfl_xor(rp[nf], 32, 64);
    }
    if (g == 0) {
      #pragma unroll
      for (int nf = 0; nf < 2; ++nf) rS[rw * 32 + nf * 16 + rr] = rp[nf];
    }
  }
  // re-zero accumulators for phase 2
  #pragma unroll
  for (int m = 0; m < 4; ++m)
    #pragma unroll
    for (int n = 0; n < 2; ++n) { acc[m][n][0]=0.f; acc[m][n][1]=0.f; acc[m][n][2]=0.f; acc[m][n][3]=0.f; }
  __syncthreads();   // transition: tS/rS visible, W2 slice 0 resident

  // hoist epilogue-2 scalars (overlap with phase-2 MFMAs)
  float mv[2], rv[2];
  #pragma unroll
  for (int nf = 0; nf < 2; ++nf) {
    const int rl = rw * 32 + nf * 16 + rr;
    mv[nf] = mask[r_base + rl];
    rv[nf] = rS[rl];
  }

  // ---- phase 2: logits = t@W2, M=k(256), N=rows(64), K=j(256) ----
  #pragma unroll
  for (int ks = 0; ks < 8; ++ks) {
    if (ks < 7) stage(W2P, 8, ks + 1, (ks + 1) & 1);
    h8 Wf[4];
    #pragma unroll
    for (int mf = 0; mf < 4; ++mf)
      Wf[mf] = *reinterpret_cast<const h8*>(&stg[ks & 1][(size_t)(mw * 4 + mf) * 512 + lane * 8]);
    h8 Bt[2];
    #pragma unroll
    for (int nf = 0; nf < 2; ++nf) {
      const int rl = rw * 32 + nf * 16 + rr;
      Bt[nf] = *reinterpret_cast<const h8*>(&tS[rl * TPITCH + ks * 32 + 8 * g]);
    }
    #pragma unroll
    for (int mf = 0; mf < 4; ++mf)
      #pragma unroll
      for (int nf = 0; nf < 2; ++nf)
        acc[mf][nf] = __builtin_amdgcn_mfma_f32_16x16x32_f16(Wf[mf], Bt[nf], acc[mf][nf], 0, 0, 0);
    if (ks < 7) __syncthreads();
  }

  // epilogue 2: masked exp; per-k sums of e and e*r over this wave's 32 rows; partial write
  float sE[4][4], sR[4][4];
  #pragma unroll
  for (int mf = 0; mf < 4; ++mf)
    #pragma unroll
    for (int reg = 0; reg < 4; ++reg) { sE[mf][reg] = 0.f; sR[mf][reg] = 0.f; }
  #pragma unroll
  for (int nf = 0; nf < 2; ++nf) {
    const float addm = (1.0f - mv[nf]) * (-1e30f);
    #pragma unroll
    for (int mf = 0; mf < 4; ++mf)
      #pragma unroll
      for (int reg = 0; reg < 4; ++reg) {
        const float e = __expf(mv[nf] * acc[mf][nf][reg] + addm);
        sE[mf][reg] += e;
        sR[mf][reg] += e * rv[nf];
      }
  }
  #pragma unroll
  for (int off = 1; off < 16; off <<= 1)
    #pragma unroll
    for (int mf = 0; mf < 4; ++mf)
      #pragma unroll
      for (int reg = 0; reg < 4; ++reg) {
        sE[mf][reg] += __shfl_xor(sE[mf][reg], off, 64);
        sR[mf][reg] += __shfl_xor(sR[mf][reg], off, 64);
      }
  if (rr == 0) {
    const int s = (blk & 63) * 2 + rw;            // 0..127 within batch
    float* pE = partE + (size_t)s * 4096 + b * 256;
    float* pR = partR + (size_t)s * 4096 + b * 256;
    #pragma unroll
    for (int mf = 0; mf < 4; ++mf)
      #pragma unroll
      for (int reg = 0; reg < 4; ++reg) {
        const int k = (mw * 4 + mf) * 16 + 4 * g + reg;
        pE[k] = sE[mf][reg];
        pR[k] = sR[mf][reg];
      }
  }
}

// ---------------- kC: reduce partials -> mu -> softmax -> cumsum -> cdf params ----------------
__global__ void kC(const float* __restrict__ partE, const float* __restrict__ partR,
                   const float* __restrict__ br, float* __restrict__ params) {
  __shared__ float red[256];
  __shared__ float sm[256];
  const int b = blockIdx.x;
  const int k = threadIdx.x;
  float v = 0.0f;
  if (k > 0) {
    const size_t idx = (size_t)b * 256 + (k - 1);
    float e0 = 0.f, e1 = 0.f, e2 = 0.f, e3 = 0.f;
    float r0 = 0.f, r1 = 0.f, r2 = 0.f, r3 = 0.f;
    #pragma unroll 4
    for (int s = 0; s < 128; s += 4) {
      e0 += partE[(size_t)(s + 0) * 4096 + idx];
      e1 += partE[(size_t)(s + 1) * 4096 + idx];
      e2 += partE[(size_t)(s + 2) * 4096 + idx];
      e3 += partE[(size_t)(s + 3) * 4096 + idx];
      r0 += partR[(size_t)(s + 0) * 4096 + idx];
      r1 += partR[(size_t)(s + 1) * 4096 + idx];
      r2 += partR[(size_t)(s + 2) * 4096 + idx];
      r3 += partR[(size_t)(s + 3) * 4096 + idx];
    }
    v = ((r0 + r1) + (r2 + r3)) / ((e0 + e1) + (e2 + e3)) + br[0];
  }
  red[k] = v; __syncthreads();
  #pragma unroll
  for (int off = 128; off > 0; off >>= 1) {
    if (k < off) red[k] = fmaxf(red[k], red[k + off]);
    __syncthreads();
  }
  const float vmax = red[0];
  __syncthreads();
  const float e = expf(v - vmax);
  red[k] = e; __syncthreads();
  #pragma unroll
  for (int off = 128; off > 0; off >>= 1) {
    if (k < off) red[k] += red[k + off];
    __syncthreads();
  }
  const float tot = red[0];
  __syncthreads();
  sm[k] = e / tot; __syncthreads();
  for (int off = 1; off < 256; off <<= 1) {
    const float add = (k >= off) ? sm[k - off] : 0.0f;
    __syncthreads();
    sm[k] += add;
    __syncthreads();
  }
  if (k < KM1) {
    const float m  = clampf(sm[k], 1e-4f, 0.9999f);
    const float a  = clampf(m - 0.0625f, 0.0f, 0.875f);
    const float bb = clampf(a + 0.125f, 0.125f, 1.0f);
    const float ba = bb - a, ma = m - a, bm = bb - m;
    float* p = params + ((size_t)b * KM1 + k) * 8;
    *reinterpret_cast<float4*>(p)     = make_float4(m, a, bb, ma / ba);
    *reinterpret_cast<float4*>(p + 4) = make_float4(1.0f / ma, bm / ba, 1.0f / bm, 0.0f);
  }
}

// ---------------- kD: gamma_scaled + almat, 128 l per block, split-k serial chains ----------------
__launch_bounds__(256)
__global__ void kD(const float* __restrict__ params, float* __restrict__ gamma,
                   float* __restrict__ almat) {
  __shared__ float P[KM1][8];
  __shared__ float gl[128];
  __shared__ float ph[128];
  const int lc = blockIdx.x, b = blockIdx.y;   // lc < 32
  const int tid = threadIdx.x;
  if (tid < KM1) {
    const float* p = params + ((size_t)b * KM1 + tid) * 8;
    *reinterpret_cast<float4*>(&P[tid][0]) = *reinterpret_cast<const float4*>(p);
    *reinterpret_cast<float4*>(&P[tid][4]) = *reinterpret_cast<const float4*>(p + 4);
  }
  __syncthreads();
  const int li = tid & 127, half = tid >> 7;
  const int l = lc * 128 + li;
  const float x = (float)l * (1.0f / 4095.0f);
  float gacc = 0.0f;
  const int k0 = half * 128, k1 = half ? KM1 : 128;
  for (int k = k0; k < k1; ++k) {
    const float m = P[k][0], a = P[k][1], bb = P[k][2], cL = P[k][3];
    const float iMA = P[k][4], cR = P[k][5], iBM = P[k][6];
    float u = clampf((x - a) * iMA, 0.0f, 1.0f);
    u = u * u; u = u * u; u = u * u; u = u * u;
    float w = clampf((bb - x) * iBM, 0.0f, 1.0f);
    w = w * w; w = w * w; w = w * w; w = w * w;
    const float left  = cL * u;
    const float right = 1.0f - cR * w;
    gacc += (x <= m) ? left : right;
  }
  if (half == 0) gl[li] = gacc; else ph[li] = gacc;
  __syncthreads();
  if (tid < 128) {
    const float tot = gl[tid] + ph[tid];
    gl[tid] = tot;
    gamma[(size_t)b * LLEN + lc * 128 + tid] = tot;
  }
  __syncthreads();
  // almat: thread -> 4 consecutive k, rows i = s*4 + (tid>>6); wave writes 1 KB contiguous
  const int kg = (tid & 63) * 4;
  const int i0 = tid >> 6;
  const float kg0 = (float)kg;
  const size_t base = ((size_t)b * LLEN + (size_t)lc * 128) * 256;
  for (int s = 0; s < 32; ++s) {
    const int i = s * 4 + i0;
    const float gv = gl[i];
    float4 v;
    v.x = fmaxf(1.0f - fabsf(gv - kg0), 0.0f);
    v.y = fmaxf(1.0f - fabsf(gv - (kg0 + 1.0f)), 0.0f);
    v.z = fmaxf(1.0f - fabsf(gv - (kg0 + 2.0f)), 0.0f);
    v.w = fmaxf(1.0f - fabsf(gv - (kg0 + 3.0f)), 0.0f);
    *reinterpret_cast<float4*>(&almat[base + (size_t)i * 256 + kg]) = v;
  }
}

extern "C" void kernel_launch(void* const* d_in, const int* in_sizes, int n_in,
                              void* d_out, int out_size, void* d_ws, size_t ws_size,
                              hipStream_t stream) {
  const float* X    = (const float*)d_in[0];
  const float* mask = (const float*)d_in[1];
  const float* W1   = (const float*)d_in[2];
  const float* b1   = (const float*)d_in[3];
  const float* W2   = (const float*)d_in[4];
  const float* Wr   = (const float*)d_in[5];
  const float* br   = (const float*)d_in[6];
  float* out   = (float*)d_out;
  float* gamma = out;
  float* almat = out + NROWS;
  // partial sums aliased in almat region (overwritten by kD afterwards):
  float* partE = almat;                    // [128][4096] f32 = 2 MB
  float* partR = almat + (size_t)128 * 4096;
  // workspace
  float* params = (float*)d_ws;                                  // [16][255][8]
  _Float16* W1P = (_Float16*)(params + (size_t)BATCH * KM1 * 8); // 64 frags * 512 halfs
  _Float16* W2P = W1P + 64 * 512;                                // 128 frags * 512 halfs

  kW<<<48, 256, 0, stream>>>(W1, W2, W1P, W2P);
  kF<<<NROWS / BR, 512, 0, stream>>>(X, W1P, W2P, b1, Wr, mask, partE, partR);
  kC<<<BATCH, 256, 0, stream>>>(partE, partR, br, params);
  kD<<<dim3(32, BATCH), 256, 0, stream>>>(params, gamma, almat);
}

// Round 9
// 86.353 us; speedup vs baseline: 2.3029x; 1.0113x over previous
//
#include <hip/hip_runtime.h>
#include <hip/hip_bf16.h>

#define LLEN 4096
#define BATCH 16
#define NROWS 65536   // BATCH*LLEN
#define DDIM 128
#define JDIM 256      // 2*D
#define KM1 255       // K-1
#define BR 128        // rows per block

typedef __attribute__((ext_vector_type(8))) _Float16 h8;
typedef __attribute__((ext_vector_type(4))) _Float16 h4;
typedef __attribute__((ext_vector_type(4))) float f4v;

typedef __attribute__((address_space(3))) void lds_t;
typedef __attribute__((address_space(1))) const void gbl_t;
__device__ __forceinline__ void g2l16(const void* g, void* l) {
  // async global->LDS, 16B per lane; LDS dest = wave-uniform base + lane*16
  __builtin_amdgcn_global_load_lds((gbl_t*)g, (lds_t*)l, 16, 0, 0);
}

__device__ __forceinline__ float clampf(float x, float lo, float hi) {
  return fminf(fmaxf(x, lo), hi);
}
__device__ __forceinline__ float tanh_fast(float x) {
  float e = __expf(2.0f * x);
  return 1.0f - 2.0f / (e + 1.0f);
}

// ---------------- kW: pack W1^T, W2^T into per-wave-contiguous fp16 MFMA fragments ----------------
// frag = 64 lanes x 8 halfs (1 KB). lane=(g*16+rr): value = WT[tile*16+rr][ks*32+8g+i].
// W1P: frag (jt*4+ks), jt<16, ks<4. W2P: frag (kt*8+ks), kt<16, ks<8 (k=255 zero-pad).
__global__ void kW(const float* __restrict__ W1, const float* __restrict__ W2,
                   _Float16* __restrict__ W1P, _Float16* __restrict__ W2P) {
  const int T = blockIdx.x * 256 + threadIdx.x;   // 192 frags * 64 lanes
  if (T >= 192 * 64) return;
  const int frag = T >> 6, lane = T & 63;
  const int rr = lane & 15, g = lane >> 4;
  if (frag < 64) {
    const int jt = frag >> 2, ks = frag & 3;
    _Float16* base = W1P + (size_t)frag * 512 + lane * 8;
    #pragma unroll
    for (int i = 0; i < 8; ++i)
      base[i] = (_Float16)W1[(ks * 32 + 8 * g + i) * JDIM + jt * 16 + rr];
  } else {
    const int f2 = frag - 64;
    const int kt = f2 >> 3, ks = f2 & 7;
    const int k = kt * 16 + rr;
    _Float16* base = W2P + (size_t)f2 * 512 + lane * 8;
    #pragma unroll
    for (int i = 0; i < 8; ++i)
      base[i] = (k < KM1) ? (_Float16)W2[(ks * 32 + 8 * g + i) * KM1 + k] : (_Float16)0.0f;
  }
}

// ---------------- kF: fused GEMM1(tanh) -> LDS t (XOR-swizzled) -> GEMM2 -> exp partials ----------------
// 128 rows/block, 8 waves (mw 4 x rw 2), per-wave 4x4 fragments. Weights via
// global_load_lds into a single 16 KB slice buffer (m97 2-barrier K-step).
__launch_bounds__(512, 4)
__global__ void kF(const float* __restrict__ X,
                   const _Float16* __restrict__ W1P, const _Float16* __restrict__ W2P,
                   const float* __restrict__ b1, const float* __restrict__ Wr,
                   const float* __restrict__ mask,
                   float* __restrict__ rbuf, float* __restrict__ partE, float* __restrict__ partR) {
  __shared__ _Float16 tS[BR * 256];    // 64 KB, index ^= (row&7)<<3 (16B-slot XOR swizzle)
  __shared__ _Float16 stgW[8192];      // 16 KB weight slice (single buffer)

  const int tid  = threadIdx.x;
  const int lane = tid & 63, wid = tid >> 6;
  const int rr = lane & 15, g = lane >> 4;
  const int mw = wid & 3;        // M quarter (j in phase1, k in phase2)
  const int rw = wid >> 2;       // row half (64 rows)
  const int blk = blockIdx.x;
  const int b = blk >> 5;        // 32 blocks per batch
  const int r_base = blk * BR;

  f4v acc[4][4];
  #pragma unroll
  for (int m = 0; m < 4; ++m)
    #pragma unroll
    for (int n = 0; n < 4; ++n) { acc[m][n][0]=0.f; acc[m][n][1]=0.f; acc[m][n][2]=0.f; acc[m][n][3]=0.f; }
  float rp[4] = {0.f, 0.f, 0.f, 0.f};

  // ---- phase 1: t = tanh(X@W1+b1), M=j(256), N=rows(128), K=d(128) ----
  #pragma unroll
  for (int ks = 0; ks < 4; ++ks) {
    if (ks) __syncthreads();           // readers of previous slice done
    {  // stage W1 slice ks: wave stages tiles wid and wid+8 (1 KB each)
      const _Float16* g0 = W1P + (size_t)(wid * 4 + ks) * 512 + lane * 8;
      const _Float16* g1 = W1P + (size_t)((wid + 8) * 4 + ks) * 512 + lane * 8;
      g2l16(g0, &stgW[wid * 512]);
      g2l16(g1, &stgW[(wid + 8) * 512]);
    }
    // X loads for this slice (independent of staging; overlap the drain)
    float4 xa[4], xb[4];
    #pragma unroll
    for (int nf = 0; nf < 4; ++nf) {
      const float* xp = X + (size_t)(r_base + rw * 64 + nf * 16 + rr) * DDIM + ks * 32 + 8 * g;
      xa[nf] = *reinterpret_cast<const float4*>(xp);
      xb[nf] = *reinterpret_cast<const float4*>(xp + 4);
    }
    if (mw == 0) {
      const float4 w0 = *reinterpret_cast<const float4*>(Wr + ks * 32 + 8 * g);
      const float4 w1 = *reinterpret_cast<const float4*>(Wr + ks * 32 + 8 * g + 4);
      #pragma unroll
      for (int nf = 0; nf < 4; ++nf)
        rp[nf] += xa[nf].x*w0.x + xa[nf].y*w0.y + xa[nf].z*w0.z + xa[nf].w*w0.w
                + xb[nf].x*w1.x + xb[nf].y*w1.y + xb[nf].z*w1.z + xb[nf].w*w1.w;
    }
    __syncthreads();                   // slice ks resident in stgW
    h8 Wf[4];
    #pragma unroll
    for (int mf = 0; mf < 4; ++mf)
      Wf[mf] = *reinterpret_cast<const h8*>(&stgW[(mw * 4 + mf) * 512 + lane * 8]);
    h8 Bx[4];
    #pragma unroll
    for (int nf = 0; nf < 4; ++nf) {
      Bx[nf][0] = (_Float16)xa[nf].x; Bx[nf][1] = (_Float16)xa[nf].y;
      Bx[nf][2] = (_Float16)xa[nf].z; Bx[nf][3] = (_Float16)xa[nf].w;
      Bx[nf][4] = (_Float16)xb[nf].x; Bx[nf][5] = (_Float16)xb[nf].y;
      Bx[nf][6] = (_Float16)xb[nf].z; Bx[nf][7] = (_Float16)xb[nf].w;
    }
    #pragma unroll
    for (int mf = 0; mf < 4; ++mf)
      #pragma unroll
      for (int nf = 0; nf < 4; ++nf)
        acc[mf][nf] = __builtin_amdgcn_mfma_f32_16x16x32_f16(Wf[mf], Bx[nf], acc[mf][nf], 0, 0, 0);
  }
  __syncthreads();                     // last W1 slice readers done -> buffer free

  // stage W2 slice 0 (overlaps epilogue-1 VALU + LDS writes)
  {
    const _Float16* g0 = W2P + (size_t)(wid * 8) * 512 + lane * 8;
    const _Float16* g1 = W2P + (size_t)((wid + 8) * 8) * 512 + lane * 8;
    g2l16(g0, &stgW[wid * 512]);
    g2l16(g1, &stgW[(wid + 8) * 512]);
  }

  // epilogue 1: bias + tanh -> fp16 tS (swizzled); fused r-dot -> rbuf (global)
  #pragma unroll
  for (int mf = 0; mf < 4; ++mf) {
    const int j0 = (mw * 4 + mf) * 16 + 4 * g;
    const float4 bv = *reinterpret_cast<const float4*>(b1 + j0);
    const float bva[4] = {bv.x, bv.y, bv.z, bv.w};
    #pragma unroll
    for (int nf = 0; nf < 4; ++nf) {
      const int rl = rw * 64 + nf * 16 + rr;
      h4 o;
      #pragma unroll
      for (int reg = 0; reg < 4; ++reg)
        o[reg] = (_Float16)tanh_fast(acc[mf][nf][reg] + bva[reg]);
      const int idx = (rl * 256 + j0) ^ ((rl & 7) << 3);
      *reinterpret_cast<h4*>(&tS[idx]) = o;
    }
  }
  if (mw == 0) {
    #pragma unroll
    for (int nf = 0; nf < 4; ++nf) {
      rp[nf] += __shfl_xor(rp[nf], 16, 64);
      rp[nf] += __shfl_xor(rp[nf], 32, 64);
    }
    if (g == 0) {
      #pragma unroll
      for (int nf = 0; nf < 4; ++nf)
        rbuf[r_base + rw * 64 + nf * 16 + rr] = rp[nf];
    }
  }
  // re-zero accumulators for phase 2
  #pragma unroll
  for (int m = 0; m < 4; ++m)
    #pragma unroll
    for (int n = 0; n < 4; ++n) { acc[m][n][0]=0.f; acc[m][n][1]=0.f; acc[m][n][2]=0.f; acc[m][n][3]=0.f; }
  __syncthreads();                     // tS + rbuf visible, W2 slice 0 resident

  // hoist epilogue-2 scalars (overlap with phase-2)
  float mv[4], rv[4];
  #pragma unroll
  for (int nf = 0; nf < 4; ++nf) {
    const int rl = rw * 64 + nf * 16 + rr;
    mv[nf] = mask[r_base + rl];
    rv[nf] = rbuf[r_base + rl];
  }

  // ---- phase 2: logits = t@W2, M=k(256), N=rows(128), K=j(256) ----
  #pragma unroll
  for (int ks = 0; ks < 8; ++ks) {
    h8 Wf[4], Bt[4];
    #pragma unroll
    for (int mf = 0; mf < 4; ++mf)
      Wf[mf] = *reinterpret_cast<const h8*>(&stgW[(mw * 4 + mf) * 512 + lane * 8]);
    #pragma unroll
    for (int nf = 0; nf < 4; ++nf) {
      const int rl = rw * 64 + nf * 16 + rr;
      const int idx = (rl * 256 + ks * 32 + 8 * g) ^ ((rl & 7) << 3);
      Bt[nf] = *reinterpret_cast<const h8*>(&tS[idx]);
    }
    #pragma unroll
    for (int mf = 0; mf < 4; ++mf)
      #pragma unroll
      for (int nf = 0; nf < 4; ++nf)
        acc[mf][nf] = __builtin_amdgcn_mfma_f32_16x16x32_f16(Wf[mf], Bt[nf], acc[mf][nf], 0, 0, 0);
    if (ks < 7) {
      __syncthreads();                 // all reads of slice ks done
      const _Float16* g0 = W2P + (size_t)(wid * 8 + ks + 1) * 512 + lane * 8;
      const _Float16* g1 = W2P + (size_t)((wid + 8) * 8 + ks + 1) * 512 + lane * 8;
      g2l16(g0, &stgW[wid * 512]);
      g2l16(g1, &stgW[(wid + 8) * 512]);
      __syncthreads();                 // slice ks+1 resident
    }
  }

  // epilogue 2: masked exp; per-k sums of e and e*r over this wave's 64 rows; partial write
  float sE[4][4], sR[4][4];
  #pragma unroll
  for (int mf = 0; mf < 4; ++mf)
    #pragma unroll
    for (int reg = 0; reg < 4; ++reg) { sE[mf][reg] = 0.f; sR[mf][reg] = 0.f; }
  #pragma unroll
  for (int nf = 0; nf < 4; ++nf) {
    const float addm = (1.0f - mv[nf]) * (-1e30f);
    #pragma unroll
    for (int mf = 0; mf < 4; ++mf)
      #pragma unroll
      for (int reg = 0; reg < 4; ++reg) {
        const float e = __expf(mv[nf] * acc[mf][nf][reg] + addm);
        sE[mf][reg] += e;
        sR[mf][reg] += e * rv[nf];
      }
  }
  #pragma unroll
  for (int off = 1; off < 16; off <<= 1)
    #pragma unroll
    for (int mf = 0; mf < 4; ++mf)
      #pragma unroll
      for (int reg = 0; reg < 4; ++reg) {
        sE[mf][reg] += __shfl_xor(sE[mf][reg], off, 64);
        sR[mf][reg] += __shfl_xor(sR[mf][reg], off, 64);
      }
  if (rr == 0) {
    const int s = (blk & 31) * 2 + rw;            // 0..63 within batch
    float* pE = partE + (size_t)s * 4096 + b * 256;
    float* pR = partR + (size_t)s * 4096 + b * 256;
    #pragma unroll
    for (int mf = 0; mf < 4; ++mf)
      #pragma unroll
      for (int reg = 0; reg < 4; ++reg) {
        const int k = (mw * 4 + mf) * 16 + 4 * g + reg;
        pE[k] = sE[mf][reg];
        pR[k] = sR[mf][reg];
      }
  }
}

// ---------------- kC: reduce 64 partials -> mu -> softmax -> cumsum -> cdf params ----------------
__global__ void kC(const float* __restrict__ partE, const float* __restrict__ partR,
                   const float* __restrict__ br, float* __restrict__ params) {
  __shared__ float red[256];
  __shared__ float sm[256];
  const int b = blockIdx.x;
  const int k = threadIdx.x;
  float v = 0.0f;
  if (k > 0) {
    const size_t idx = (size_t)b * 256 + (k - 1);
    float e0 = 0.f, e1 = 0.f, e2 = 0.f, e3 = 0.f;
    float r0 = 0.f, r1 = 0.f, r2 = 0.f, r3 = 0.f;
    #pragma unroll 4
    for (int s = 0; s < 64; s += 4) {
      e0 += partE[(size_t)(s + 0) * 4096 + idx];
      e1 += partE[(size_t)(s + 1) * 4096 + idx];
      e2 += partE[(size_t)(s + 2) * 4096 + idx];
      e3 += partE[(size_t)(s + 3) * 4096 + idx];
      r0 += partR[(size_t)(s + 0) * 4096 + idx];
      r1 += partR[(size_t)(s + 1) * 4096 + idx];
      r2 += partR[(size_t)(s + 2) * 4096 + idx];
      r3 += partR[(size_t)(s + 3) * 4096 + idx];
    }
    v = ((r0 + r1) + (r2 + r3)) / ((e0 + e1) + (e2 + e3)) + br[0];
  }
  red[k] = v; __syncthreads();
  #pragma unroll
  for (int off = 128; off > 0; off >>= 1) {
    if (k < off) red[k] = fmaxf(red[k], red[k + off]);
    __syncthreads();
  }
  const float vmax = red[0];
  __syncthreads();
  const float e = expf(v - vmax);
  red[k] = e; __syncthreads();
  #pragma unroll
  for (int off = 128; off > 0; off >>= 1) {
    if (k < off) red[k] += red[k + off];
    __syncthreads();
  }
  const float tot = red[0];
  __syncthreads();
  sm[k] = e / tot; __syncthreads();
  for (int off = 1; off < 256; off <<= 1) {
    const float add = (k >= off) ? sm[k - off] : 0.0f;
    __syncthreads();
    sm[k] += add;
    __syncthreads();
  }
  if (k < KM1) {
    const float m  = clampf(sm[k], 1e-4f, 0.9999f);
    const float a  = clampf(m - 0.0625f, 0.0f, 0.875f);
    const float bb = clampf(a + 0.125f, 0.125f, 1.0f);
    const float ba = bb - a, ma = m - a, bm = bb - m;
    float* p = params + ((size_t)b * KM1 + k) * 8;
    *reinterpret_cast<float4*>(p)     = make_float4(m, a, bb, ma / ba);
    *reinterpret_cast<float4*>(p + 4) = make_float4(1.0f / ma, bm / ba, 1.0f / bm, 0.0f);
  }
}

// ---------------- kD: gamma_scaled + almat, 128 l per block, split-k serial chains ----------------
__launch_bounds__(256)
__global__ void kD(const float* __restrict__ params, float* __restrict__ gamma,
                   float* __restrict__ almat) {
  __shared__ float P[KM1][8];
  __shared__ float gl[128];
  __shared__ float ph[128];
  const int lc = blockIdx.x, b = blockIdx.y;   // lc < 32
  const int tid = threadIdx.x;
  if (tid < KM1) {
    const float* p = params + ((size_t)b * KM1 + tid) * 8;
    *reinterpret_cast<float4*>(&P[tid][0]) = *reinterpret_cast<const float4*>(p);
    *reinterpret_cast<float4*>(&P[tid][4]) = *reinterpret_cast<const float4*>(p + 4);
  }
  __syncthreads();
  const int li = tid & 127, half = tid >> 7;
  const int l = lc * 128 + li;
  const float x = (float)l * (1.0f / 4095.0f);
  float gacc = 0.0f;
  const int k0 = half * 128, k1 = half ? KM1 : 128;
  for (int k = k0; k < k1; ++k) {
    const float m = P[k][0], a = P[k][1], bb = P[k][2], cL = P[k][3];
    const float iMA = P[k][4], cR = P[k][5], iBM = P[k][6];
    float u = clampf((x - a) * iMA, 0.0f, 1.0f);
    u = u * u; u = u * u; u = u * u; u = u * u;
    float w = clampf((bb - x) * iBM, 0.0f, 1.0f);
    w = w * w; w = w * w; w = w * w; w = w * w;
    const float left  = cL * u;
    const float right = 1.0f - cR * w;
    gacc += (x <= m) ? left : right;
  }
  if (half == 0) gl[li] = gacc; else ph[li] = gacc;
  __syncthreads();
  if (tid < 128) {
    const float tot = gl[tid] + ph[tid];
    gl[tid] = tot;
    gamma[(size_t)b * LLEN + lc * 128 + tid] = tot;
  }
  __syncthreads();
  // almat: thread -> 4 consecutive k, rows i = s*4 + (tid>>6); wave writes 1 KB contiguous
  const int kg = (tid & 63) * 4;
  const int i0 = tid >> 6;
  const float kg0 = (float)kg;
  const size_t base = ((size_t)b * LLEN + (size_t)lc * 128) * 256;
  for (int s = 0; s < 32; ++s) {
    const int i = s * 4 + i0;
    const float gv = gl[i];
    float4 v;
    v.x = fmaxf(1.0f - fabsf(gv - kg0), 0.0f);
    v.y = fmaxf(1.0f - fabsf(gv - (kg0 + 1.0f)), 0.0f);
    v.z = fmaxf(1.0f - fabsf(gv - (kg0 + 2.0f)), 0.0f);
    v.w = fmaxf(1.0f - fabsf(gv - (kg0 + 3.0f)), 0.0f);
    *reinterpret_cast<float4*>(&almat[base + (size_t)i * 256 + kg]) = v;
  }
}

extern "C" void kernel_launch(void* const* d_in, const int* in_sizes, int n_in,
                              void* d_out, int out_size, void* d_ws, size_t ws_size,
                              hipStream_t stream) {
  const float* X    = (const float*)d_in[0];
  const float* mask = (const float*)d_in[1];
  const float* W1   = (const float*)d_in[2];
  const float* b1   = (const float*)d_in[3];
  const float* W2   = (const float*)d_in[4];
  const float* Wr   = (const float*)d_in[5];
  const float* br   = (const float*)d_in[6];
  float* out   = (float*)d_out;
  float* gamma = out;
  float* almat = out + NROWS;
  // scratch aliased in d_out (fully overwritten by kD afterwards):
  float* rbuf  = gamma;                    // 65536 f32: r = X.Wr
  float* partE = almat;                    // [64][4096] f32 = 1 MB
  float* partR = almat + (size_t)64 * 4096;
  // workspace
  float* params = (float*)d_ws;                                  // [16][255][8]
  _Float16* W1P = (_Float16*)(params + (size_t)BATCH * KM1 * 8); // 64 frags * 512 halfs
  _Float16* W2P = W1P + 64 * 512;                                // 128 frags * 512 halfs

  kW<<<48, 256, 0, stream>>>(W1, W2, W1P, W2P);
  kF<<<NROWS / BR, 512, 0, stream>>>(X, W1P, W2P, b1, Wr, mask, rbuf, partE, partR);
  kC<<<BATCH, 256, 0, stream>>>(partE, partR, br, params);
  kD<<<dim3(32, BATCH), 256, 0, stream>>>(params, gamma, almat);
}

// Round 10
// 84.109 us; speedup vs baseline: 2.3643x; 1.0267x over previous
//
#include <hip/hip_runtime.h>
#include <hip/hip_bf16.h>

#define LLEN 4096
#define BATCH 16
#define NROWS 65536   // BATCH*LLEN
#define DDIM 128
#define JDIM 256      // 2*D
#define KM1 255       // K-1
#define BR 64         // rows per block
#define TPITCH 266    // t LDS pitch in halfs (133 dwords -> odd bank stride)

typedef __attribute__((ext_vector_type(8))) _Float16 h8;
typedef __attribute__((ext_vector_type(4))) _Float16 h4;
typedef __attribute__((ext_vector_type(4))) float f4v;

__device__ __forceinline__ float clampf(float x, float lo, float hi) {
  return fminf(fmaxf(x, lo), hi);
}
__device__ __forceinline__ float tanh_fast(float x) {
  float e = __expf(2.0f * x);
  return 1.0f - 2.0f / (e + 1.0f);
}

// ---------------- kW: pack W1^T, W2^T into per-wave-contiguous fp16 MFMA fragments ----------------
// frag = 64 lanes x 8 halfs (1 KB). lane=(g*16+rr): value = WT[tile*16+rr][ks*32+8g+i].
// W1P: frag (jt*4+ks), jt<16, ks<4. W2P: frag (kt*8+ks), kt<16, ks<8 (k=255 zero-pad).
__global__ void kW(const float* __restrict__ W1, const float* __restrict__ W2,
                   _Float16* __restrict__ W1P, _Float16* __restrict__ W2P) {
  const int T = blockIdx.x * 256 + threadIdx.x;   // 192 frags * 64 lanes
  if (T >= 192 * 64) return;
  const int frag = T >> 6, lane = T & 63;
  const int rr = lane & 15, g = lane >> 4;
  if (frag < 64) {
    const int jt = frag >> 2, ks = frag & 3;
    _Float16* base = W1P + (size_t)frag * 512 + lane * 8;
    #pragma unroll
    for (int i = 0; i < 8; ++i)
      base[i] = (_Float16)W1[(ks * 32 + 8 * g + i) * JDIM + jt * 16 + rr];
  } else {
    const int f2 = frag - 64;
    const int kt = f2 >> 3, ks = f2 & 7;
    const int k = kt * 16 + rr;
    _Float16* base = W2P + (size_t)f2 * 512 + lane * 8;
    #pragma unroll
    for (int i = 0; i < 8; ++i)
      base[i] = (k < KM1) ? (_Float16)W2[(ks * 32 + 8 * g + i) * KM1 + k] : (_Float16)0.0f;
  }
}

// ---------------- kF: fused GEMM1(tanh) -> LDS t -> GEMM2 -> exp partial sums ----------------
// R5-proven shape: 64 rows/block, 8 waves, depth-1 register prefetch, one barrier, no atomics.
__launch_bounds__(512, 4)
__global__ void kF(const float* __restrict__ X,
                   const _Float16* __restrict__ W1P, const _Float16* __restrict__ W2P,
                   const float* __restrict__ b1, const float* __restrict__ Wr,
                   const float* __restrict__ mask,
                   float* __restrict__ partE, float* __restrict__ partR) {
  __shared__ _Float16 tS[BR * TPITCH];   // 34,048 B
  __shared__ float rS[BR];

  const int tid  = threadIdx.x;
  const int lane = tid & 63, wid = tid >> 6;
  const int rr = lane & 15, g = lane >> 4;
  const int mw = wid & 3;        // M quarter (j in phase1, k in phase2)
  const int rw = wid >> 2;       // row half (32 rows)
  const int blk = blockIdx.x;
  const int b = blk >> 6;        // 64 blocks per batch
  const int r_base = blk * BR;

  f4v acc[4][2];
  #pragma unroll
  for (int m = 0; m < 4; ++m)
    #pragma unroll
    for (int n = 0; n < 2; ++n) { acc[m][n][0]=0.f; acc[m][n][1]=0.f; acc[m][n][2]=0.f; acc[m][n][3]=0.f; }
  float rp[2] = {0.f, 0.f};

  // ---- phase 1: t = tanh(X@W1+b1), M=j(256), N=rows(64), K=d(128). Pipelined, no barriers. ----
  h8 Wc[4], Wn[4];
  #pragma unroll
  for (int mf = 0; mf < 4; ++mf)
    Wc[mf] = *reinterpret_cast<const h8*>(W1P + (size_t)((mw * 4 + mf) * 4) * 512 + lane * 8);
  float4 xc[2][2], xn[2][2];
  #pragma unroll
  for (int nf = 0; nf < 2; ++nf) {
    const float* xp = X + (size_t)(r_base + rw * 32 + nf * 16 + rr) * DDIM + 8 * g;
    xc[nf][0] = *reinterpret_cast<const float4*>(xp);
    xc[nf][1] = *reinterpret_cast<const float4*>(xp + 4);
  }
  #pragma unroll
  for (int ks = 0; ks < 4; ++ks) {
    if (ks < 3) {
      #pragma unroll
      for (int mf = 0; mf < 4; ++mf)
        Wn[mf] = *reinterpret_cast<const h8*>(W1P + (size_t)((mw * 4 + mf) * 4 + ks + 1) * 512 + lane * 8);
      #pragma unroll
      for (int nf = 0; nf < 2; ++nf) {
        const float* xp = X + (size_t)(r_base + rw * 32 + nf * 16 + rr) * DDIM + (ks + 1) * 32 + 8 * g;
        xn[nf][0] = *reinterpret_cast<const float4*>(xp);
        xn[nf][1] = *reinterpret_cast<const float4*>(xp + 4);
      }
    }
    h8 Bx[2];
    #pragma unroll
    for (int nf = 0; nf < 2; ++nf) {
      const float xv[8] = {xc[nf][0].x, xc[nf][0].y, xc[nf][0].z, xc[nf][0].w,
                           xc[nf][1].x, xc[nf][1].y, xc[nf][1].z, xc[nf][1].w};
      #pragma unroll
      for (int i = 0; i < 8; ++i) Bx[nf][i] = (_Float16)xv[i];
      if (mw == 0) {
        const float4 w0 = *reinterpret_cast<const float4*>(Wr + ks * 32 + 8 * g);
        const float4 w1 = *reinterpret_cast<const float4*>(Wr + ks * 32 + 8 * g + 4);
        rp[nf] += xv[0]*w0.x + xv[1]*w0.y + xv[2]*w0.z + xv[3]*w0.w
                + xv[4]*w1.x + xv[5]*w1.y + xv[6]*w1.z + xv[7]*w1.w;
      }
    }
    #pragma unroll
    for (int mf = 0; mf < 4; ++mf)
      #pragma unroll
      for (int nf = 0; nf < 2; ++nf)
        acc[mf][nf] = __builtin_amdgcn_mfma_f32_16x16x32_f16(Wc[mf], Bx[nf], acc[mf][nf], 0, 0, 0);
    if (ks < 3) {
      #pragma unroll
      for (int mf = 0; mf < 4; ++mf) Wc[mf] = Wn[mf];
      #pragma unroll
      for (int nf = 0; nf < 2; ++nf) { xc[nf][0] = xn[nf][0]; xc[nf][1] = xn[nf][1]; }
    }
  }

  // hoist phase-2 weight frags: issue now so they land during tanh + barrier
  #pragma unroll
  for (int mf = 0; mf < 4; ++mf)
    Wc[mf] = *reinterpret_cast<const h8*>(W2P + (size_t)((mw * 4 + mf) * 8) * 512 + lane * 8);

  // epilogue 1: bias + tanh -> fp16 tS; fused r-dot -> rS
  #pragma unroll
  for (int mf = 0; mf < 4; ++mf) {
    const int j0 = (mw * 4 + mf) * 16 + 4 * g;
    const float4 bv = *reinterpret_cast<const float4*>(b1 + j0);
    const float bva[4] = {bv.x, bv.y, bv.z, bv.w};
    #pragma unroll
    for (int nf = 0; nf < 2; ++nf) {
      const int rl = rw * 32 + nf * 16 + rr;
      h4 o;
      #pragma unroll
      for (int reg = 0; reg < 4; ++reg)
        o[reg] = (_Float16)tanh_fast(acc[mf][nf][reg] + bva[reg]);
      *reinterpret_cast<h4*>(&tS[rl * TPITCH + j0]) = o;
    }
  }
  if (mw == 0) {
    #pragma unroll
    for (int nf = 0; nf < 2; ++nf) {
      rp[nf] += __shfl_xor(rp[nf], 16, 64);
      rp[nf] += __shfl_xor(rp[nf], 32, 64);
    }
    if (g == 0) {
      #pragma unroll
      for (int nf = 0; nf < 2; ++nf) rS[rw * 32 + nf * 16 + rr] = rp[nf];
    }
  }
  // re-zero accumulators for phase 2
  #pragma unroll
  for (int m = 0; m < 4; ++m)
    #pragma unroll
    for (int n = 0; n < 2; ++n) { acc[m][n][0]=0.f; acc[m][n][1]=0.f; acc[m][n][2]=0.f; acc[m][n][3]=0.f; }
  __syncthreads();   // the only barrier

  // hoist epilogue-2 scalars (overlap with phase-2 MFMAs)
  float mv[2], rv[2];
  #pragma unroll
  for (int nf = 0; nf < 2; ++nf) {
    const int rl = rw * 32 + nf * 16 + rr;
    mv[nf] = mask[r_base + rl];
    rv[nf] = rS[rl];
  }

  // ---- phase 2: logits = t@W2, M=k(256), N=rows(64), K=j(256). Pipelined, no barriers. ----
  #pragma unroll
  for (int ks = 0; ks < 8; ++ks) {
    if (ks < 7) {
      #pragma unroll
      for (int mf = 0; mf < 4; ++mf)
        Wn[mf] = *reinterpret_cast<const h8*>(W2P + (size_t)((mw * 4 + mf) * 8 + ks + 1) * 512 + lane * 8);
    }
    h8 Bt[2];
    #pragma unroll
    for (int nf = 0; nf < 2; ++nf) {
      const int rl = rw * 32 + nf * 16 + rr;
      Bt[nf] = *reinterpret_cast<const h8*>(&tS[rl * TPITCH + ks * 32 + 8 * g]);
    }
    #pragma unroll
    for (int mf = 0; mf < 4; ++mf)
      #pragma unroll
      for (int nf = 0; nf < 2; ++nf)
        acc[mf][nf] = __builtin_amdgcn_mfma_f32_16x16x32_f16(Wc[mf], Bt[nf], acc[mf][nf], 0, 0, 0);
    if (ks < 7) {
      #pragma unroll
      for (int mf = 0; mf < 4; ++mf) Wc[mf] = Wn[mf];
    }
  }

  // epilogue 2: masked exp; per-k sums of e and e*r over this wave's 32 rows; partial write
  float sE[4][4], sR[4][4];
  #pragma unroll
  for (int mf = 0; mf < 4; ++mf)
    #pragma unroll
    for (int reg = 0; reg < 4; ++reg) { sE[mf][reg] = 0.f; sR[mf][reg] = 0.f; }
  #pragma unroll
  for (int nf = 0; nf < 2; ++nf) {
    const float addm = (1.0f - mv[nf]) * (-1e30f);
    #pragma unroll
    for (int mf = 0; mf < 4; ++mf)
      #pragma unroll
      for (int reg = 0; reg < 4; ++reg) {
        const float e = __expf(mv[nf] * acc[mf][nf][reg] + addm);
        sE[mf][reg] += e;
        sR[mf][reg] += e * rv[nf];
      }
  }
  #pragma unroll
  for (int off = 1; off < 16; off <<= 1)
    #pragma unroll
    for (int mf = 0; mf < 4; ++mf)
      #pragma unroll
      for (int reg = 0; reg < 4; ++reg) {
        sE[mf][reg] += __shfl_xor(sE[mf][reg], off, 64);
        sR[mf][reg] += __shfl_xor(sR[mf][reg], off, 64);
      }
  if (rr == 0) {
    const int s = (blk & 63) * 2 + rw;            // 0..127 within batch
    float* pE = partE + (size_t)s * 4096 + b * 256;
    float* pR = partR + (size_t)s * 4096 + b * 256;
    #pragma unroll
    for (int mf = 0; mf < 4; ++mf)
      #pragma unroll
      for (int reg = 0; reg < 4; ++reg) {
        const int k = (mw * 4 + mf) * 16 + 4 * g + reg;
        pE[k] = sE[mf][reg];
        pR[k] = sR[mf][reg];
      }
  }
}

// ---------------- kC: reduce 128 partials (16-deep batched loads) -> mu -> softmax -> cdf params ----------------
__global__ void kC(const float* __restrict__ partE, const float* __restrict__ partR,
                   const float* __restrict__ br, float* __restrict__ params) {
  __shared__ float red[256];
  __shared__ float sm[256];
  const int b = blockIdx.x;
  const int k = threadIdx.x;
  float v = 0.0f;
  if (k > 0) {
    const size_t idx = (size_t)b * 256 + (k - 1);
    float esum = 0.0f, rsum = 0.0f;
    #pragma unroll
    for (int s0 = 0; s0 < 128; s0 += 16) {
      float te[16], tr[16];
      #pragma unroll
      for (int i = 0; i < 16; ++i) te[i] = partE[(size_t)(s0 + i) * 4096 + idx];
      #pragma unroll
      for (int i = 0; i < 16; ++i) tr[i] = partR[(size_t)(s0 + i) * 4096 + idx];
      float e = 0.0f, r = 0.0f;
      #pragma unroll
      for (int i = 0; i < 16; ++i) { e += te[i]; r += tr[i]; }
      esum += e; rsum += r;
    }
    v = rsum / esum + br[0];
  }
  red[k] = v; __syncthreads();
  #pragma unroll
  for (int off = 128; off > 0; off >>= 1) {
    if (k < off) red[k] = fmaxf(red[k], red[k + off]);
    __syncthreads();
  }
  const float vmax = red[0];
  __syncthreads();
  const float e = expf(v - vmax);
  red[k] = e; __syncthreads();
  #pragma unroll
  for (int off = 128; off > 0; off >>= 1) {
    if (k < off) red[k] += red[k + off];
    __syncthreads();
  }
  const float tot = red[0];
  __syncthreads();
  sm[k] = e / tot; __syncthreads();
  for (int off = 1; off < 256; off <<= 1) {
    const float add = (k >= off) ? sm[k - off] : 0.0f;
    __syncthreads();
    sm[k] += add;
    __syncthreads();
  }
  if (k < KM1) {
    const float m  = clampf(sm[k], 1e-4f, 0.9999f);
    const float a  = clampf(m - 0.0625f, 0.0f, 0.875f);
    const float bb = clampf(a + 0.125f, 0.125f, 1.0f);
    const float ba = bb - a, ma = m - a, bm = bb - m;
    float* p = params + ((size_t)b * KM1 + k) * 8;
    *reinterpret_cast<float4*>(p)     = make_float4(m, a, bb, ma / ba);
    *reinterpret_cast<float4*>(p + 4) = make_float4(1.0f / ma, bm / ba, 1.0f / bm, 0.0f);
  }
}

// ---------------- kD: gamma_scaled + almat, 128 l per block, split-k serial chains ----------------
__launch_bounds__(256)
__global__ void kD(const float* __restrict__ params, float* __restrict__ gamma,
                   float* __restrict__ almat) {
  __shared__ float P[KM1][8];
  __shared__ float gl[128];
  __shared__ float ph[128];
  const int lc = blockIdx.x, b = blockIdx.y;   // lc < 32
  const int tid = threadIdx.x;
  if (tid < KM1) {
    const float* p = params + ((size_t)b * KM1 + tid) * 8;
    *reinterpret_cast<float4*>(&P[tid][0]) = *reinterpret_cast<const float4*>(p);
    *reinterpret_cast<float4*>(&P[tid][4]) = *reinterpret_cast<const float4*>(p + 4);
  }
  __syncthreads();
  const int li = tid & 127, half = tid >> 7;
  const int l = lc * 128 + li;
  const float x = (float)l * (1.0f / 4095.0f);
  float gacc = 0.0f;
  const int k0 = half * 128, k1 = half ? KM1 : 128;
  for (int k = k0; k < k1; ++k) {
    const float m = P[k][0], a = P[k][1], bb = P[k][2], cL = P[k][3];
    const float iMA = P[k][4], cR = P[k][5], iBM = P[k][6];
    float u = clampf((x - a) * iMA, 0.0f, 1.0f);
    u = u * u; u = u * u; u = u * u; u = u * u;
    float w = clampf((bb - x) * iBM, 0.0f, 1.0f);
    w = w * w; w = w * w; w = w * w; w = w * w;
    const float left  = cL * u;
    const float right = 1.0f - cR * w;
    gacc += (x <= m) ? left : right;
  }
  if (half == 0) gl[li] = gacc; else ph[li] = gacc;
  __syncthreads();
  if (tid < 128) {
    const float tot = gl[tid] + ph[tid];
    gl[tid] = tot;
    gamma[(size_t)b * LLEN + lc * 128 + tid] = tot;
  }
  __syncthreads();
  // almat: thread -> 4 consecutive k, rows i = s*4 + (tid>>6); wave writes 1 KB contiguous
  const int kg = (tid & 63) * 4;
  const int i0 = tid >> 6;
  const float kg0 = (float)kg;
  const size_t base = ((size_t)b * LLEN + (size_t)lc * 128) * 256;
  for (int s = 0; s < 32; ++s) {
    const int i = s * 4 + i0;
    const float gv = gl[i];
    float4 v;
    v.x = fmaxf(1.0f - fabsf(gv - kg0), 0.0f);
    v.y = fmaxf(1.0f - fabsf(gv - (kg0 + 1.0f)), 0.0f);
    v.z = fmaxf(1.0f - fabsf(gv - (kg0 + 2.0f)), 0.0f);
    v.w = fmaxf(1.0f - fabsf(gv - (kg0 + 3.0f)), 0.0f);
    *reinterpret_cast<float4*>(&almat[base + (size_t)i * 256 + kg]) = v;
  }
}

extern "C" void kernel_launch(void* const* d_in, const int* in_sizes, int n_in,
                              void* d_out, int out_size, void* d_ws, size_t ws_size,
                              hipStream_t stream) {
  const float* X    = (const float*)d_in[0];
  const float* mask = (const float*)d_in[1];
  const float* W1   = (const float*)d_in[2];
  const float* b1   = (const float*)d_in[3];
  const float* W2   = (const float*)d_in[4];
  const float* Wr   = (const float*)d_in[5];
  const float* br   = (const float*)d_in[6];
  float* out   = (float*)d_out;
  float* gamma = out;
  float* almat = out + NROWS;
  // partial sums aliased in almat region (overwritten by kD afterwards):
  float* partE = almat;                    // [128][4096] f32 = 2 MB
  float* partR = almat + (size_t)128 * 4096;
  // workspace
  float* params = (float*)d_ws;                                  // [16][255][8]
  _Float16* W1P = (_Float16*)(params + (size_t)BATCH * KM1 * 8); // 64 frags * 512 halfs
  _Float16* W2P = W1P + 64 * 512;                                // 128 frags * 512 halfs

  kW<<<48, 256, 0, stream>>>(W1, W2, W1P, W2P);
  kF<<<NROWS / BR, 512, 0, stream>>>(X, W1P, W2P, b1, Wr, mask, partE, partR);
  kC<<<BATCH, 256, 0, stream>>>(partE, partR, br, params);
  kD<<<dim3(32, BATCH), 256, 0, stream>>>(params, gamma, almat);
}